// Round 6
// baseline (363.653 us; speedup 1.0000x reference)
//
#include <hip/hip_runtime.h>
#include <math.h>

// QSAR fused pipeline, one block per molecule. B=4096, A=64, D=6, AF=37, BF=6, H=128.
// deg==6 atoms (P~91%) output ZERO from both convs -> conv worklist (~5.8 atoms/block).
// 96% of work atoms have deg==5 -> stage W1[5]/W2[5] k-tiles in LDS (shared by units);
// P5 stages Wo k-tiles in LDS with register prefetch. Spill discipline (R2 lesson):
// named registers, unconditional accumulators, conditional writes, uniform barriers.
// R5 bugfix: conv1 tile-2 FMA must cover feature rows 32..36 ONLY (5 rows, not 11);
// weight rows 37..42 are the bsum rows, handled by the dedicated s_bsum tail.

__device__ __forceinline__ float4 max4(float4 a, float4 b) {
  return make_float4(fmaxf(a.x, b.x), fmaxf(a.y, b.y), fmaxf(a.z, b.z), fmaxf(a.w, b.w));
}

__device__ __forceinline__ float4 nbr_max(const float4* sx4, const int* se, int a, int c4) {
  float4 m = sx4[a * 32 + c4];
#pragma unroll
  for (int d = 0; d < 6; ++d) {
    int e = se[a * 6 + d];
    if (e >= 0) m = max4(m, sx4[e * 32 + c4]);
  }
  return m;
}

__device__ __forceinline__ float4 nbr_sum(const float4* sx4, const int* se, int a, int c4) {
  float4 s = sx4[a * 32 + c4];
#pragma unroll
  for (int d = 0; d < 6; ++d) {
    int e = se[a * 6 + d];
    if (e >= 0) {
      float4 v = sx4[e * 32 + c4];
      s.x += v.x; s.y += v.y; s.z += v.z; s.w += v.w;
    }
  }
  return s;
}

// pool2: max over WORK members only; non-work x2 rows are implicitly 0, relu>=0 -> 0-init exact.
__device__ __forceinline__ float4 nbr_wmax(const float4* sx4, const int* se, const int* sdeg,
                                           int a, int c4) {
  float4 m = make_float4(0.f, 0.f, 0.f, 0.f);
  if (sdeg[a] < 6) m = max4(m, sx4[a * 32 + c4]);
#pragma unroll
  for (int d = 0; d < 6; ++d) {
    int e = se[a * 6 + d];
    if (e >= 0 && sdeg[e] < 6) m = max4(m, sx4[e * 32 + c4]);
  }
  return m;
}

__global__ __launch_bounds__(256, 4) void qsar_fused(
    const float* __restrict__ atoms, const float* __restrict__ bonds,
    const int* __restrict__ edges,
    const float* __restrict__ W1, const float* __restrict__ b1,
    const float* __restrict__ W2, const float* __restrict__ b2,
    const float* __restrict__ Wo, const float* __restrict__ bo,
    const float* __restrict__ Wm1, const float* __restrict__ bm1,
    const float* __restrict__ Wm2, const float* __restrict__ bm2,
    const float* __restrict__ Wm3, const float* __restrict__ bm3,
    float* __restrict__ out)
{
  const int b    = blockIdx.x;
  const int tid  = threadIdx.x;
  const int hid  = tid >> 5;   // half-wave unit id 0..7
  const int hl   = tid & 31;   // lane in half-wave

  __shared__ float s_x[64 * 128];     // x1 -> x1p -> ysum -> x2 -> x2p -> logits -> probs
  __shared__ float s_wt[16 * 128];    // staged weight k-tile (8 KB), shared by P1/P3/P5
  __shared__ float s_wtail[6 * 128];  // staged Wo tail rows 128..133 (3 KB)
  __shared__ float s_sa[352];         // conv1 gather (8x38=304); later fp(256)+h1(64)+h2(32)
  __shared__ float s_bsum[64 * 8];
  __shared__ int   s_edges[64 * 6];
  __shared__ int   s_deg[64];
  __shared__ int   s_work[64];        // deg<6 atoms
  __shared__ int   s_perm[64];        // nonzero-x2p atoms [0,na), zero atoms [na,64)
  __shared__ float s_rsum[64];
  __shared__ int   s_nwork, s_na, s_nz;

  float4* sx4      = reinterpret_cast<float4*>(s_x);
  float4* s_wt4    = reinterpret_cast<float4*>(s_wt);
  float4* s_wtail4 = reinterpret_cast<float4*>(s_wtail);
  float*  s_fp = s_sa;
  float*  s_h1 = s_sa + 256;
  float*  s_h2 = s_sa + 320;

  // ---------------- P0: stage edges, bsum; zero s_x; reset counters -------------------
  {
    const int* ge = edges + (size_t)b * (64 * 6);
    for (int i = tid; i < 64 * 6; i += 256) s_edges[i] = ge[i];
    const float* gb = bonds + (size_t)b * (64 * 36);
    for (int i = tid; i < 64 * 6; i += 256) {
      int a = i / 6, f = i - a * 6;
      float s = 0.f;
#pragma unroll
      for (int d = 0; d < 6; ++d) s += gb[a * 36 + d * 6 + f];
      s_bsum[a * 8 + f] = s;
    }
#pragma unroll
    for (int j = 0; j < 8; ++j) sx4[tid + j * 256] = make_float4(0.f, 0.f, 0.f, 0.f);
    if (tid == 0) { s_nwork = 0; s_na = 0; s_nz = 0; }
  }
  __syncthreads();

  // ---------------- P0b: degree + worklist --------------------------------------------
  if (tid < 64) {
    int dcnt = 0;
#pragma unroll
    for (int d = 0; d < 6; ++d) dcnt += (s_edges[tid * 6 + d] >= 0) ? 1 : 0;
    s_deg[tid] = dcnt;
    if (dcnt < 6) { int p = atomicAdd(&s_nwork, 1); s_work[p] = tid; }
  }
  __syncthreads();

  // ---------------- P0c: perm (nonzero-x2p first; read only in P5) --------------------
  if (tid < 64) {
    int nzf = (s_deg[tid] < 6) ? 1 : 0;
#pragma unroll
    for (int d = 0; d < 6; ++d) {
      int e = s_edges[tid * 6 + d];
      if (e >= 0 && s_deg[e] < 6) nzf = 1;
    }
    if (nzf) { int p = atomicAdd(&s_na, 1); s_perm[p] = tid; }
    else     { int p = atomicAdd(&s_nz, 1); s_perm[63 - p] = tid; }
  }

  // ---------------- P1: conv1, chunks of <=8 atoms, W1[5] k-tiles staged in LDS -------
  // Feature rows: 0..36 from s_sa (tiles of 16,16,5). Weight rows 37..42 are bsum rows,
  // handled ONLY by the s_bsum tail below (R5 bug: tile-2 FMA ran 11 rows -> read pad).
  {
    const int nw = s_nwork;
    const float* ga = atoms + (size_t)b * (64 * 37);
    const float4* W1_5f4 = reinterpret_cast<const float4*>(W1 + 5 * (43 * 128));
    const int c0 = hl * 4;
    for (int cb = 0; cb < nw; cb += 8) {
      const int cnt = (nw - cb < 8) ? (nw - cb) : 8;
      // gather summed feats (self + valid members) from global into s_sa
      for (int i = tid; i < cnt * 37; i += 256) {
        int wi = i / 37, k = i - wi * 37;
        int a = s_work[cb + wi];
        float f = ga[a * 37 + k];
#pragma unroll
        for (int d = 0; d < 6; ++d) {
          int e = s_edges[a * 6 + d];
          if (e >= 0) f += ga[e * 37 + k];
        }
        s_sa[wi * 38 + k] = f;
      }
      __syncthreads();
      const bool have = (hid < cnt);
      const int a = have ? s_work[cb + hid] : 0;
      const int d = have ? s_deg[a] : 5;        // work atoms: d in [0,5]
      const float4* wdf4 = reinterpret_cast<const float4*>(W1 + d * (43 * 128));
      float4 acc = *reinterpret_cast<const float4*>(&b1[d * 128 + c0]);
#pragma unroll
      for (int t = 0; t < 3; ++t) {
        const int kt0 = t * 16;
        const int rows_sa = (t < 2) ? 16 : 5;   // ATOM-feature rows only (37 total)
        const int nf4 = rows_sa * 32;
        const int f2i = tid * 2;
        if (f2i < nf4)     s_wt4[f2i]     = W1_5f4[kt0 * 32 + f2i];
        if (f2i + 1 < nf4) s_wt4[f2i + 1] = W1_5f4[kt0 * 32 + f2i + 1];
        __syncthreads();
        if (have) {
          if (d == 5) {
            for (int k = 0; k < rows_sa; ++k) {
              const float ff = s_sa[hid * 38 + kt0 + k];
              const float4 w4 = s_wt4[k * 32 + hl];
              acc.x = fmaf(ff, w4.x, acc.x); acc.y = fmaf(ff, w4.y, acc.y);
              acc.z = fmaf(ff, w4.z, acc.z); acc.w = fmaf(ff, w4.w, acc.w);
            }
          } else {
            for (int k = 0; k < rows_sa; ++k) {
              const float ff = s_sa[hid * 38 + kt0 + k];
              const float4 w4 = wdf4[(kt0 + k) * 32 + hl];
              acc.x = fmaf(ff, w4.x, acc.x); acc.y = fmaf(ff, w4.y, acc.y);
              acc.z = fmaf(ff, w4.z, acc.z); acc.w = fmaf(ff, w4.w, acc.w);
            }
          }
        }
        __syncthreads();
      }
      if (have) {
#pragma unroll
        for (int kk = 0; kk < 6; ++kk) {
          const float ff = s_bsum[a * 8 + kk];
          const float4 w4 = wdf4[(37 + kk) * 32 + hl];
          acc.x = fmaf(ff, w4.x, acc.x); acc.y = fmaf(ff, w4.y, acc.y);
          acc.z = fmaf(ff, w4.z, acc.z); acc.w = fmaf(ff, w4.w, acc.w);
        }
        *reinterpret_cast<float4*>(&s_x[a * 128 + c0]) =
            make_float4(fmaxf(acc.x, 0.f), fmaxf(acc.y, 0.f),
                        fmaxf(acc.z, 0.f), fmaxf(acc.w, 0.f));
      }
    }
  }
  __syncthreads();

  // ---------------- P2: pool1 in place (all rows), float4 -----------------------------
  {
    float4 v0 = nbr_max(sx4, s_edges, (tid + 0 * 256) >> 5, tid & 31);
    float4 v1 = nbr_max(sx4, s_edges, (tid + 1 * 256) >> 5, tid & 31);
    float4 v2 = nbr_max(sx4, s_edges, (tid + 2 * 256) >> 5, tid & 31);
    float4 v3 = nbr_max(sx4, s_edges, (tid + 3 * 256) >> 5, tid & 31);
    float4 v4 = nbr_max(sx4, s_edges, (tid + 4 * 256) >> 5, tid & 31);
    float4 v5 = nbr_max(sx4, s_edges, (tid + 5 * 256) >> 5, tid & 31);
    float4 v6 = nbr_max(sx4, s_edges, (tid + 6 * 256) >> 5, tid & 31);
    float4 v7 = nbr_max(sx4, s_edges, (tid + 7 * 256) >> 5, tid & 31);
    __syncthreads();
    sx4[tid + 0 * 256] = v0; sx4[tid + 1 * 256] = v1;
    sx4[tid + 2 * 256] = v2; sx4[tid + 3 * 256] = v3;
    sx4[tid + 4 * 256] = v4; sx4[tid + 5 * 256] = v5;
    sx4[tid + 6 * 256] = v6; sx4[tid + 7 * 256] = v7;
  }
  __syncthreads();

  // ---------------- P2b: ysum for work rows in place ----------------------------------
  {
    const float4 z = make_float4(0.f, 0.f, 0.f, 0.f);
    float4 v0 = z, v1 = z, v2 = z, v3 = z, v4 = z, v5 = z, v6 = z, v7 = z;
    if (s_deg[(tid + 0 * 256) >> 5] < 6) v0 = nbr_sum(sx4, s_edges, (tid + 0 * 256) >> 5, tid & 31);
    if (s_deg[(tid + 1 * 256) >> 5] < 6) v1 = nbr_sum(sx4, s_edges, (tid + 1 * 256) >> 5, tid & 31);
    if (s_deg[(tid + 2 * 256) >> 5] < 6) v2 = nbr_sum(sx4, s_edges, (tid + 2 * 256) >> 5, tid & 31);
    if (s_deg[(tid + 3 * 256) >> 5] < 6) v3 = nbr_sum(sx4, s_edges, (tid + 3 * 256) >> 5, tid & 31);
    if (s_deg[(tid + 4 * 256) >> 5] < 6) v4 = nbr_sum(sx4, s_edges, (tid + 4 * 256) >> 5, tid & 31);
    if (s_deg[(tid + 5 * 256) >> 5] < 6) v5 = nbr_sum(sx4, s_edges, (tid + 5 * 256) >> 5, tid & 31);
    if (s_deg[(tid + 6 * 256) >> 5] < 6) v6 = nbr_sum(sx4, s_edges, (tid + 6 * 256) >> 5, tid & 31);
    if (s_deg[(tid + 7 * 256) >> 5] < 6) v7 = nbr_sum(sx4, s_edges, (tid + 7 * 256) >> 5, tid & 31);
    __syncthreads();
    if (s_deg[(tid + 0 * 256) >> 5] < 6) sx4[tid + 0 * 256] = v0;
    if (s_deg[(tid + 1 * 256) >> 5] < 6) sx4[tid + 1 * 256] = v1;
    if (s_deg[(tid + 2 * 256) >> 5] < 6) sx4[tid + 2 * 256] = v2;
    if (s_deg[(tid + 3 * 256) >> 5] < 6) sx4[tid + 3 * 256] = v3;
    if (s_deg[(tid + 4 * 256) >> 5] < 6) sx4[tid + 4 * 256] = v4;
    if (s_deg[(tid + 5 * 256) >> 5] < 6) sx4[tid + 5 * 256] = v5;
    if (s_deg[(tid + 6 * 256) >> 5] < 6) sx4[tid + 6 * 256] = v6;
    if (s_deg[(tid + 7 * 256) >> 5] < 6) sx4[tid + 7 * 256] = v7;
  }
  __syncthreads();

  // ---------------- P3: conv2, W2[5] k-tiles staged in LDS + register prefetch --------
  // Unit (half-wave) reads ONLY its own row; write after all its reads. deg!=5 (~4% of
  // work atoms) falls back to direct L2 reads inside the same tile loop.
  {
    const int nw = s_nwork;
    const int c0 = hl * 4;
    const float4* W2_5f4 = reinterpret_cast<const float4*>(W2 + 5 * (134 * 128));
    for (int g = 0; g < nw; g += 8) {
      const bool have = (g + hid < nw);
      const int a = have ? s_work[g + hid] : 0;
      const int d = have ? s_deg[a] : 5;
      const float4* wdf4 = reinterpret_cast<const float4*>(W2 + d * (134 * 128));
      float4 acc = *reinterpret_cast<const float4*>(&b2[d * 128 + c0]);
      float4 p0 = W2_5f4[2 * tid], p1 = W2_5f4[2 * tid + 1];   // prefetch tile 0
      for (int kt = 0; kt < 8; ++kt) {
        s_wt4[2 * tid] = p0; s_wt4[2 * tid + 1] = p1;
        __syncthreads();
        const int ktn = (kt < 7) ? kt + 1 : 7;
        p0 = W2_5f4[ktn * 512 + 2 * tid]; p1 = W2_5f4[ktn * 512 + 2 * tid + 1];
        if (have) {
          const float* xr = &s_x[a * 128 + kt * 16];
          if (d == 5) {
#pragma unroll
            for (int k = 0; k < 16; ++k) {
              const float ff = xr[k];
              const float4 w4 = s_wt4[k * 32 + hl];
              acc.x = fmaf(ff, w4.x, acc.x); acc.y = fmaf(ff, w4.y, acc.y);
              acc.z = fmaf(ff, w4.z, acc.z); acc.w = fmaf(ff, w4.w, acc.w);
            }
          } else {
#pragma unroll 4
            for (int k = 0; k < 16; ++k) {
              const float ff = xr[k];
              const float4 w4 = wdf4[(kt * 16 + k) * 32 + hl];
              acc.x = fmaf(ff, w4.x, acc.x); acc.y = fmaf(ff, w4.y, acc.y);
              acc.z = fmaf(ff, w4.z, acc.z); acc.w = fmaf(ff, w4.w, acc.w);
            }
          }
        }
        __syncthreads();
      }
      if (have) {
#pragma unroll
        for (int kk = 0; kk < 6; ++kk) {
          const float ff = s_bsum[a * 8 + kk];
          const float4 w4 = wdf4[(128 + kk) * 32 + hl];
          acc.x = fmaf(ff, w4.x, acc.x); acc.y = fmaf(ff, w4.y, acc.y);
          acc.z = fmaf(ff, w4.z, acc.z); acc.w = fmaf(ff, w4.w, acc.w);
        }
        *reinterpret_cast<float4*>(&s_x[a * 128 + c0]) =
            make_float4(fmaxf(acc.x, 0.f), fmaxf(acc.y, 0.f),
                        fmaxf(acc.z, 0.f), fmaxf(acc.w, 0.f));
      }
    }
  }
  __syncthreads();

  // ---------------- P4: pool2 in place, work members only, 0-init ---------------------
  {
    float4 v0 = nbr_wmax(sx4, s_edges, s_deg, (tid + 0 * 256) >> 5, tid & 31);
    float4 v1 = nbr_wmax(sx4, s_edges, s_deg, (tid + 1 * 256) >> 5, tid & 31);
    float4 v2 = nbr_wmax(sx4, s_edges, s_deg, (tid + 2 * 256) >> 5, tid & 31);
    float4 v3 = nbr_wmax(sx4, s_edges, s_deg, (tid + 3 * 256) >> 5, tid & 31);
    float4 v4 = nbr_wmax(sx4, s_edges, s_deg, (tid + 4 * 256) >> 5, tid & 31);
    float4 v5 = nbr_wmax(sx4, s_edges, s_deg, (tid + 5 * 256) >> 5, tid & 31);
    float4 v6 = nbr_wmax(sx4, s_edges, s_deg, (tid + 6 * 256) >> 5, tid & 31);
    float4 v7 = nbr_wmax(sx4, s_edges, s_deg, (tid + 7 * 256) >> 5, tid & 31);
    __syncthreads();
    sx4[tid + 0 * 256] = v0; sx4[tid + 1 * 256] = v1;
    sx4[tid + 2 * 256] = v2; sx4[tid + 3 * 256] = v3;
    sx4[tid + 4 * 256] = v4; sx4[tid + 5 * 256] = v5;
    sx4[tid + 6 * 256] = v6; sx4[tid + 7 * 256] = v7;
  }
  __syncthreads();

  // ---------------- P5: logits GEMM, Wo k-tiles staged in LDS + register prefetch -----
  // Round j: group (half-wave) ag owns perm slots 32j+4ag..+3; groups fully past na
  // skip FMAs (their slots' rows are exactly zero anyway). Writes are conditional and
  // happen after the tile loop's final barrier (all reads of round j complete).
  {
    const int cg = hl;
    const int c0 = cg * 4;
    const int na = s_na;
    const int nr = (na + 31) >> 5;
    const float4* Wof4 = reinterpret_cast<const float4*>(Wo);
    // stage Wo tail rows 128..133 once (visible after any later barrier)
    for (int i = tid; i < 768; i += 256) s_wtail[i] = Wo[128 * 128 + i];
    for (int j = 0; j < nr; ++j) {
      const int sl = j * 32 + hid * 4;
      const bool act = (sl < na);
      const int at0 = s_perm[sl + 0], at1 = s_perm[sl + 1];
      const int at2 = s_perm[sl + 2], at3 = s_perm[sl + 3];
      float a00 = 0.f, a01 = 0.f, a02 = 0.f, a03 = 0.f;
      float a10 = 0.f, a11 = 0.f, a12 = 0.f, a13 = 0.f;
      float a20 = 0.f, a21 = 0.f, a22 = 0.f, a23 = 0.f;
      float a30 = 0.f, a31 = 0.f, a32 = 0.f, a33 = 0.f;
      float4 p0 = Wof4[2 * tid], p1 = Wof4[2 * tid + 1];   // prefetch tile 0
      for (int kt = 0; kt < 8; ++kt) {
        s_wt4[2 * tid] = p0; s_wt4[2 * tid + 1] = p1;
        __syncthreads();
        const int ktn = (kt < 7) ? kt + 1 : 7;
        p0 = Wof4[ktn * 512 + 2 * tid]; p1 = Wof4[ktn * 512 + 2 * tid + 1];
        if (act) {
#pragma unroll
          for (int k = 0; k < 16; ++k) {
            const float4 w4 = s_wt4[k * 32 + cg];
            const int kb = kt * 16 + k;
            const float f0 = s_x[at0 * 128 + kb], f1 = s_x[at1 * 128 + kb];
            const float f2 = s_x[at2 * 128 + kb], f3 = s_x[at3 * 128 + kb];
            a00 = fmaf(f0, w4.x, a00); a01 = fmaf(f0, w4.y, a01);
            a02 = fmaf(f0, w4.z, a02); a03 = fmaf(f0, w4.w, a03);
            a10 = fmaf(f1, w4.x, a10); a11 = fmaf(f1, w4.y, a11);
            a12 = fmaf(f1, w4.z, a12); a13 = fmaf(f1, w4.w, a13);
            a20 = fmaf(f2, w4.x, a20); a21 = fmaf(f2, w4.y, a21);
            a22 = fmaf(f2, w4.z, a22); a23 = fmaf(f2, w4.w, a23);
            a30 = fmaf(f3, w4.x, a30); a31 = fmaf(f3, w4.y, a31);
            a32 = fmaf(f3, w4.z, a32); a33 = fmaf(f3, w4.w, a33);
          }
        }
        __syncthreads();
      }
      if (act) {
#pragma unroll
        for (int kk = 0; kk < 6; ++kk) {
          const float4 w4 = s_wtail4[kk * 32 + cg];
          const float f0 = s_bsum[at0 * 8 + kk], f1 = s_bsum[at1 * 8 + kk];
          const float f2 = s_bsum[at2 * 8 + kk], f3 = s_bsum[at3 * 8 + kk];
          a00 = fmaf(f0, w4.x, a00); a01 = fmaf(f0, w4.y, a01);
          a02 = fmaf(f0, w4.z, a02); a03 = fmaf(f0, w4.w, a03);
          a10 = fmaf(f1, w4.x, a10); a11 = fmaf(f1, w4.y, a11);
          a12 = fmaf(f1, w4.z, a12); a13 = fmaf(f1, w4.w, a13);
          a20 = fmaf(f2, w4.x, a20); a21 = fmaf(f2, w4.y, a21);
          a22 = fmaf(f2, w4.z, a22); a23 = fmaf(f2, w4.w, a23);
          a30 = fmaf(f3, w4.x, a30); a31 = fmaf(f3, w4.y, a31);
          a32 = fmaf(f3, w4.z, a32); a33 = fmaf(f3, w4.w, a33);
        }
      }
      const float4 bo4 = *reinterpret_cast<const float4*>(bo + c0);
      if (sl + 0 < na)
        *reinterpret_cast<float4*>(&s_x[at0 * 128 + c0]) =
            make_float4(a00 + bo4.x, a01 + bo4.y, a02 + bo4.z, a03 + bo4.w);
      if (sl + 1 < na)
        *reinterpret_cast<float4*>(&s_x[at1 * 128 + c0]) =
            make_float4(a10 + bo4.x, a11 + bo4.y, a12 + bo4.z, a13 + bo4.w);
      if (sl + 2 < na)
        *reinterpret_cast<float4*>(&s_x[at2 * 128 + c0]) =
            make_float4(a20 + bo4.x, a21 + bo4.y, a22 + bo4.z, a23 + bo4.w);
      if (sl + 3 < na)
        *reinterpret_cast<float4*>(&s_x[at3 * 128 + c0]) =
            make_float4(a30 + bo4.x, a31 + bo4.y, a32 + bo4.z, a33 + bo4.w);
    }
    __syncthreads();   // round writes done; s_wtail visible even when nr==0
    // zero-x2p atoms: logits = bo + bsum . Wo[128:134] (tail from LDS)
    const int nz = 64 - na;
    for (int e = tid; e < nz * 128; e += 256) {
      int zi = e >> 7, c = e & 127;
      int a = s_perm[na + zi];
      float acc = bo[c];
#pragma unroll
      for (int kk = 0; kk < 6; ++kk)
        acc = fmaf(s_bsum[a * 8 + kk], s_wtail[kk * 128 + c], acc);
      s_x[a * 128 + c] = acc;
    }
  }
  __syncthreads();

  // ---------------- P6: per-atom softmax over 128, 4 lanes/atom, in registers ---------
  {
    const int a = tid >> 2, q = tid & 3;
    float* base = &s_x[a * 128 + q * 32];
    const float4 v0 = *reinterpret_cast<const float4*>(base + ((0 + tid) & 7) * 4);
    const float4 v1 = *reinterpret_cast<const float4*>(base + ((1 + tid) & 7) * 4);
    const float4 v2 = *reinterpret_cast<const float4*>(base + ((2 + tid) & 7) * 4);
    const float4 v3 = *reinterpret_cast<const float4*>(base + ((3 + tid) & 7) * 4);
    const float4 v4 = *reinterpret_cast<const float4*>(base + ((4 + tid) & 7) * 4);
    const float4 v5 = *reinterpret_cast<const float4*>(base + ((5 + tid) & 7) * 4);
    const float4 v6 = *reinterpret_cast<const float4*>(base + ((6 + tid) & 7) * 4);
    const float4 v7 = *reinterpret_cast<const float4*>(base + ((7 + tid) & 7) * 4);
    float mx = fmaxf(fmaxf(fmaxf(v0.x, v0.y), fmaxf(v0.z, v0.w)),
                     fmaxf(fmaxf(v1.x, v1.y), fmaxf(v1.z, v1.w)));
    mx = fmaxf(mx, fmaxf(fmaxf(fmaxf(v2.x, v2.y), fmaxf(v2.z, v2.w)),
                         fmaxf(fmaxf(v3.x, v3.y), fmaxf(v3.z, v3.w))));
    mx = fmaxf(mx, fmaxf(fmaxf(fmaxf(v4.x, v4.y), fmaxf(v4.z, v4.w)),
                         fmaxf(fmaxf(v5.x, v5.y), fmaxf(v5.z, v5.w))));
    mx = fmaxf(mx, fmaxf(fmaxf(fmaxf(v6.x, v6.y), fmaxf(v6.z, v6.w)),
                         fmaxf(fmaxf(v7.x, v7.y), fmaxf(v7.z, v7.w))));
    mx = fmaxf(mx, __shfl_xor(mx, 1));
    mx = fmaxf(mx, __shfl_xor(mx, 2));
    float sm = 0.f;
    float4 e0, e1, e2, e3, e4, e5, e6, e7;
    e0.x = __expf(v0.x - mx); e0.y = __expf(v0.y - mx); e0.z = __expf(v0.z - mx); e0.w = __expf(v0.w - mx);
    e1.x = __expf(v1.x - mx); e1.y = __expf(v1.y - mx); e1.z = __expf(v1.z - mx); e1.w = __expf(v1.w - mx);
    e2.x = __expf(v2.x - mx); e2.y = __expf(v2.y - mx); e2.z = __expf(v2.z - mx); e2.w = __expf(v2.w - mx);
    e3.x = __expf(v3.x - mx); e3.y = __expf(v3.y - mx); e3.z = __expf(v3.z - mx); e3.w = __expf(v3.w - mx);
    e4.x = __expf(v4.x - mx); e4.y = __expf(v4.y - mx); e4.z = __expf(v4.z - mx); e4.w = __expf(v4.w - mx);
    e5.x = __expf(v5.x - mx); e5.y = __expf(v5.y - mx); e5.z = __expf(v5.z - mx); e5.w = __expf(v5.w - mx);
    e6.x = __expf(v6.x - mx); e6.y = __expf(v6.y - mx); e6.z = __expf(v6.z - mx); e6.w = __expf(v6.w - mx);
    e7.x = __expf(v7.x - mx); e7.y = __expf(v7.y - mx); e7.z = __expf(v7.z - mx); e7.w = __expf(v7.w - mx);
    sm += e0.x + e0.y + e0.z + e0.w; sm += e1.x + e1.y + e1.z + e1.w;
    sm += e2.x + e2.y + e2.z + e2.w; sm += e3.x + e3.y + e3.z + e3.w;
    sm += e4.x + e4.y + e4.z + e4.w; sm += e5.x + e5.y + e5.z + e5.w;
    sm += e6.x + e6.y + e6.z + e6.w; sm += e7.x + e7.y + e7.z + e7.w;
    *reinterpret_cast<float4*>(base + ((0 + tid) & 7) * 4) = e0;
    *reinterpret_cast<float4*>(base + ((1 + tid) & 7) * 4) = e1;
    *reinterpret_cast<float4*>(base + ((2 + tid) & 7) * 4) = e2;
    *reinterpret_cast<float4*>(base + ((3 + tid) & 7) * 4) = e3;
    *reinterpret_cast<float4*>(base + ((4 + tid) & 7) * 4) = e4;
    *reinterpret_cast<float4*>(base + ((5 + tid) & 7) * 4) = e5;
    *reinterpret_cast<float4*>(base + ((6 + tid) & 7) * 4) = e6;
    *reinterpret_cast<float4*>(base + ((7 + tid) & 7) * 4) = e7;
    sm += __shfl_xor(sm, 1);
    sm += __shfl_xor(sm, 2);
    if (q == 0) s_rsum[a] = (s_deg[a] != 0) ? (1.f / sm) : 0.f;
  }
  __syncthreads();

  // ---------------- P7: fingerprint (s_fp aliases dead s_sa) --------------------------
  {
    const int c = tid & 127, half = tid >> 7;
    float s = 0.f;
    for (int a2 = half * 32; a2 < half * 32 + 32; ++a2)
      s = fmaf(s_x[a2 * 128 + c], s_rsum[a2], s);
    s_fp[half * 128 + c] = s;
  }
  __syncthreads();
  if (tid < 128) s_fp[tid] += s_fp[128 + tid];
  __syncthreads();

  // ---------------- P8: MLP head ------------------------------------------------------
  if (tid < 64) {
    float acc = bm1[tid];
    for (int k = 0; k < 128; ++k) acc = fmaf(s_fp[k], Wm1[k * 64 + tid], acc);
    s_h1[tid] = fmaxf(acc, 0.f);
  }
  __syncthreads();
  if (tid < 32) {
    float acc = bm2[tid];
    for (int k = 0; k < 64; ++k) acc = fmaf(s_h1[k], Wm2[k * 32 + tid], acc);
    s_h2[tid] = fmaxf(acc, 0.f);
  }
  __syncthreads();
  if (tid < 64) {
    float p = (tid < 32) ? s_h2[tid] * Wm3[tid] : 0.f;
#pragma unroll
    for (int off = 32; off > 0; off >>= 1) p += __shfl_xor(p, off);
    if (tid == 0) out[b] = p + bm3[0];
  }
}

extern "C" void kernel_launch(void* const* d_in, const int* in_sizes, int n_in,
                              void* d_out, int out_size, void* d_ws, size_t ws_size,
                              hipStream_t stream) {
  const float* atoms = (const float*)d_in[0];
  const float* bonds = (const float*)d_in[1];
  const int*   edges = (const int*)d_in[2];
  const float* W1  = (const float*)d_in[3];
  const float* b1  = (const float*)d_in[4];
  const float* W2  = (const float*)d_in[5];
  const float* b2  = (const float*)d_in[6];
  const float* Wo  = (const float*)d_in[7];
  const float* bo  = (const float*)d_in[8];
  const float* Wm1 = (const float*)d_in[9];
  const float* bm1 = (const float*)d_in[10];
  const float* Wm2 = (const float*)d_in[11];
  const float* bm2 = (const float*)d_in[12];
  const float* Wm3 = (const float*)d_in[13];
  const float* bm3 = (const float*)d_in[14];
  float* out = (float*)d_out;

  const int B = out_size;  // 4096 molecules
  qsar_fused<<<dim3(B), dim3(256), 0, stream>>>(
      atoms, bonds, edges, W1, b1, W2, b2, Wo, bo,
      Wm1, bm1, Wm2, bm2, Wm3, bm3, out);
}

// Round 7
// 238.860 us; speedup vs baseline: 1.5224x; 1.5224x over previous
//
#include <hip/hip_runtime.h>
#include <math.h>

// QSAR fused pipeline, ONE BLOCK OF 512 THREADS PER MOLECULE.
// B=4096, A=64, D=6, AF=37, BF=6, H=128.
// Rationale (R6 post-mortem): LDS/molecule is fixed (~39 KB); 512-thread blocks give
// 4 blocks/CU = 32 waves/CU (100% occupancy ceiling) vs 16 waves at 256 threads.
// Weight staging reverted (R6: 6.6M bank conflicts, occ 20%). Direct L2 weight loads
// (R4-proven). Spill discipline: named regs, unconditional accumulators, conditional
// writes, uniform barriers. launch_bounds(512,8) caps VGPR at 64 (R4 measured 52).

__device__ __forceinline__ float4 max4(float4 a, float4 b) {
  return make_float4(fmaxf(a.x, b.x), fmaxf(a.y, b.y), fmaxf(a.z, b.z), fmaxf(a.w, b.w));
}

__device__ __forceinline__ float4 nbr_max(const float4* sx4, const int* se, int a, int c4) {
  float4 m = sx4[a * 32 + c4];
#pragma unroll
  for (int d = 0; d < 6; ++d) {
    int e = se[a * 6 + d];
    if (e >= 0) m = max4(m, sx4[e * 32 + c4]);
  }
  return m;
}

__device__ __forceinline__ float4 nbr_sum(const float4* sx4, const int* se, int a, int c4) {
  float4 s = sx4[a * 32 + c4];
#pragma unroll
  for (int d = 0; d < 6; ++d) {
    int e = se[a * 6 + d];
    if (e >= 0) {
      float4 v = sx4[e * 32 + c4];
      s.x += v.x; s.y += v.y; s.z += v.z; s.w += v.w;
    }
  }
  return s;
}

// pool2: max over WORK members only; non-work x2 rows are implicitly 0, relu>=0 -> 0-init exact.
__device__ __forceinline__ float4 nbr_wmax(const float4* sx4, const int* se, const int* sdeg,
                                           int a, int c4) {
  float4 m = make_float4(0.f, 0.f, 0.f, 0.f);
  if (sdeg[a] < 6) m = max4(m, sx4[a * 32 + c4]);
#pragma unroll
  for (int d = 0; d < 6; ++d) {
    int e = se[a * 6 + d];
    if (e >= 0 && sdeg[e] < 6) m = max4(m, sx4[e * 32 + c4]);
  }
  return m;
}

__global__ __launch_bounds__(512, 8) void qsar_fused(
    const float* __restrict__ atoms, const float* __restrict__ bonds,
    const int* __restrict__ edges,
    const float* __restrict__ W1, const float* __restrict__ b1,
    const float* __restrict__ W2, const float* __restrict__ b2,
    const float* __restrict__ Wo, const float* __restrict__ bo,
    const float* __restrict__ Wm1, const float* __restrict__ bm1,
    const float* __restrict__ Wm2, const float* __restrict__ bm2,
    const float* __restrict__ Wm3, const float* __restrict__ bm3,
    float* __restrict__ out)
{
  const int b    = blockIdx.x;
  const int tid  = threadIdx.x;        // 0..511
  const int hid  = tid >> 5;           // half-wave unit id 0..15
  const int hl   = tid & 31;           // lane in half-wave

  __shared__ float s_x[64 * 128];      // 32768 B
  __shared__ float s_sa[608];          // conv1 gather 16x38; later fp(512)+h1(64)+h2(32)
  __shared__ float s_bsum[64 * 8];     // 2048 B
  __shared__ int   s_edges[64 * 6];    // 1536 B
  __shared__ int   s_deg[64];
  __shared__ int   s_work[64];         // deg<6 atoms
  __shared__ int   s_perm[64];         // nonzero-x2p atoms [0,na), zero atoms [na,64)
  __shared__ float s_rsum[64];
  __shared__ int   s_nwork, s_na, s_nz;

  float4* sx4  = reinterpret_cast<float4*>(s_x);
  float*  s_fp = s_sa;                 // 512 floats (4 partials x 128)
  float*  s_h1 = s_sa + 512;           // 64
  float*  s_h2 = s_sa + 576;           // 32

  // ---------------- P0: stage edges, bsum; zero s_x; reset counters -------------------
  {
    const int* ge = edges + (size_t)b * (64 * 6);
    for (int i = tid; i < 64 * 6; i += 512) s_edges[i] = ge[i];
    const float* gb = bonds + (size_t)b * (64 * 36);
    for (int i = tid; i < 64 * 6; i += 512) {
      int a = i / 6, f = i - a * 6;
      float s = 0.f;
#pragma unroll
      for (int d = 0; d < 6; ++d) s += gb[a * 36 + d * 6 + f];
      s_bsum[a * 8 + f] = s;
    }
#pragma unroll
    for (int j = 0; j < 4; ++j) sx4[tid + j * 512] = make_float4(0.f, 0.f, 0.f, 0.f);
    if (tid == 0) { s_nwork = 0; s_na = 0; s_nz = 0; }
  }
  __syncthreads();

  // ---------------- P0b: degree + worklist --------------------------------------------
  if (tid < 64) {
    int dcnt = 0;
#pragma unroll
    for (int d = 0; d < 6; ++d) dcnt += (s_edges[tid * 6 + d] >= 0) ? 1 : 0;
    s_deg[tid] = dcnt;
    if (dcnt < 6) { int p = atomicAdd(&s_nwork, 1); s_work[p] = tid; }
  }
  __syncthreads();

  // ---------------- P0c: perm (nonzero-x2p first; read only in P5) --------------------
  if (tid < 64) {
    int nzf = (s_deg[tid] < 6) ? 1 : 0;
#pragma unroll
    for (int d = 0; d < 6; ++d) {
      int e = s_edges[tid * 6 + d];
      if (e >= 0 && s_deg[e] < 6) nzf = 1;
    }
    if (nzf) { int p = atomicAdd(&s_na, 1); s_perm[p] = tid; }
    else     { int p = atomicAdd(&s_nz, 1); s_perm[63 - p] = tid; }
  }

  // ---------------- P1: conv1, 16 half-wave GEMV units, chunks of <=16 work atoms -----
  {
    const int nw = s_nwork;
    const float* ga = atoms + (size_t)b * (64 * 37);
    const int c0 = hl * 4;
    for (int cb = 0; cb < nw; cb += 16) {
      const int cnt = (nw - cb < 16) ? (nw - cb) : 16;
      // gather summed feats (self + valid members) from global into s_sa
      for (int i = tid; i < cnt * 37; i += 512) {
        int wi = i / 37, k = i - wi * 37;
        int a = s_work[cb + wi];
        float f = ga[a * 37 + k];
#pragma unroll
        for (int d = 0; d < 6; ++d) {
          int e = s_edges[a * 6 + d];
          if (e >= 0) f += ga[e * 37 + k];
        }
        s_sa[wi * 38 + k] = f;
      }
      __syncthreads();
      // half-wave GEMV: 4 cols/lane, float4 weight rows; writes own s_x row (pre-zeroed)
      for (int w = hid; w < cnt; w += 16) {
        const int a = s_work[cb + w];
        const int d = s_deg[a];
        const float4* wdf4 = reinterpret_cast<const float4*>(W1 + d * (43 * 128));
        float4 acc = *reinterpret_cast<const float4*>(&b1[d * 128 + c0]);
#pragma unroll 4
        for (int k = 0; k < 37; ++k) {
          const float ff = s_sa[w * 38 + k];
          const float4 w4 = wdf4[k * 32 + hl];
          acc.x = fmaf(ff, w4.x, acc.x); acc.y = fmaf(ff, w4.y, acc.y);
          acc.z = fmaf(ff, w4.z, acc.z); acc.w = fmaf(ff, w4.w, acc.w);
        }
#pragma unroll
        for (int kk = 0; kk < 6; ++kk) {
          const float ff = s_bsum[a * 8 + kk];
          const float4 w4 = wdf4[(37 + kk) * 32 + hl];
          acc.x = fmaf(ff, w4.x, acc.x); acc.y = fmaf(ff, w4.y, acc.y);
          acc.z = fmaf(ff, w4.z, acc.z); acc.w = fmaf(ff, w4.w, acc.w);
        }
        *reinterpret_cast<float4*>(&s_x[a * 128 + c0]) =
            make_float4(fmaxf(acc.x, 0.f), fmaxf(acc.y, 0.f),
                        fmaxf(acc.z, 0.f), fmaxf(acc.w, 0.f));
      }
      __syncthreads();
    }
  }
  __syncthreads();

  // ---------------- P2: pool1 in place (all rows), float4, 4 elems/thread -------------
  {
    float4 v0 = nbr_max(sx4, s_edges, (tid + 0 * 512) >> 5, tid & 31);
    float4 v1 = nbr_max(sx4, s_edges, (tid + 1 * 512) >> 5, tid & 31);
    float4 v2 = nbr_max(sx4, s_edges, (tid + 2 * 512) >> 5, tid & 31);
    float4 v3 = nbr_max(sx4, s_edges, (tid + 3 * 512) >> 5, tid & 31);
    __syncthreads();
    sx4[tid + 0 * 512] = v0; sx4[tid + 1 * 512] = v1;
    sx4[tid + 2 * 512] = v2; sx4[tid + 3 * 512] = v3;
  }
  __syncthreads();

  // ---------------- P2b: ysum for work rows in place ----------------------------------
  {
    const float4 z = make_float4(0.f, 0.f, 0.f, 0.f);
    float4 v0 = z, v1 = z, v2 = z, v3 = z;
    if (s_deg[(tid + 0 * 512) >> 5] < 6) v0 = nbr_sum(sx4, s_edges, (tid + 0 * 512) >> 5, tid & 31);
    if (s_deg[(tid + 1 * 512) >> 5] < 6) v1 = nbr_sum(sx4, s_edges, (tid + 1 * 512) >> 5, tid & 31);
    if (s_deg[(tid + 2 * 512) >> 5] < 6) v2 = nbr_sum(sx4, s_edges, (tid + 2 * 512) >> 5, tid & 31);
    if (s_deg[(tid + 3 * 512) >> 5] < 6) v3 = nbr_sum(sx4, s_edges, (tid + 3 * 512) >> 5, tid & 31);
    __syncthreads();
    if (s_deg[(tid + 0 * 512) >> 5] < 6) sx4[tid + 0 * 512] = v0;
    if (s_deg[(tid + 1 * 512) >> 5] < 6) sx4[tid + 1 * 512] = v1;
    if (s_deg[(tid + 2 * 512) >> 5] < 6) sx4[tid + 2 * 512] = v2;
    if (s_deg[(tid + 3 * 512) >> 5] < 6) sx4[tid + 3 * 512] = v3;
  }
  __syncthreads();

  // ---------------- P3: conv2, 16 half-wave units, own-row read / own-row write -------
  // All reads of row a (wave-lockstep) precede the write. Rows across units disjoint.
  {
    const int nw = s_nwork;
    const int c0 = hl * 4;
    for (int w = hid; w < nw; w += 16) {
      const int a = s_work[w];
      const int d = s_deg[a];
      const float4* wdf4 = reinterpret_cast<const float4*>(W2 + d * (134 * 128));
      float4 acc = *reinterpret_cast<const float4*>(&b2[d * 128 + c0]);
#pragma unroll 4
      for (int k = 0; k < 128; ++k) {
        const float ff = s_x[a * 128 + k];
        const float4 w4 = wdf4[k * 32 + hl];
        acc.x = fmaf(ff, w4.x, acc.x); acc.y = fmaf(ff, w4.y, acc.y);
        acc.z = fmaf(ff, w4.z, acc.z); acc.w = fmaf(ff, w4.w, acc.w);
      }
#pragma unroll
      for (int kk = 0; kk < 6; ++kk) {
        const float ff = s_bsum[a * 8 + kk];
        const float4 w4 = wdf4[(128 + kk) * 32 + hl];
        acc.x = fmaf(ff, w4.x, acc.x); acc.y = fmaf(ff, w4.y, acc.y);
        acc.z = fmaf(ff, w4.z, acc.z); acc.w = fmaf(ff, w4.w, acc.w);
      }
      *reinterpret_cast<float4*>(&s_x[a * 128 + c0]) =
          make_float4(fmaxf(acc.x, 0.f), fmaxf(acc.y, 0.f),
                      fmaxf(acc.z, 0.f), fmaxf(acc.w, 0.f));
    }
  }
  __syncthreads();

  // ---------------- P4: pool2 in place, work members only, 0-init ---------------------
  {
    float4 v0 = nbr_wmax(sx4, s_edges, s_deg, (tid + 0 * 512) >> 5, tid & 31);
    float4 v1 = nbr_wmax(sx4, s_edges, s_deg, (tid + 1 * 512) >> 5, tid & 31);
    float4 v2 = nbr_wmax(sx4, s_edges, s_deg, (tid + 2 * 512) >> 5, tid & 31);
    float4 v3 = nbr_wmax(sx4, s_edges, s_deg, (tid + 3 * 512) >> 5, tid & 31);
    __syncthreads();
    sx4[tid + 0 * 512] = v0; sx4[tid + 1 * 512] = v1;
    sx4[tid + 2 * 512] = v2; sx4[tid + 3 * 512] = v3;
  }
  __syncthreads();

  // ---------------- P5: logits GEMM, ONE round: 16 groups x 4 perm slots = 64 rows ----
  // Group hid owns slots 4*hid..4*hid+3. Groups with sl<na run the dense 128-k loop
  // (straddle group's >=na slots have exactly-zero x2p rows -> dense adds 0 -> still
  // correct). ALL groups do the bsum tail + bias and write their 4 rows. Each row is
  // read and written only by its owner group (same wave, program order) -> no barrier.
  {
    const int c0 = hl * 4;
    const int na = s_na;
    const int sl = hid * 4;
    const int at0 = s_perm[sl + 0], at1 = s_perm[sl + 1];
    const int at2 = s_perm[sl + 2], at3 = s_perm[sl + 3];
    float a00 = 0.f, a01 = 0.f, a02 = 0.f, a03 = 0.f;
    float a10 = 0.f, a11 = 0.f, a12 = 0.f, a13 = 0.f;
    float a20 = 0.f, a21 = 0.f, a22 = 0.f, a23 = 0.f;
    float a30 = 0.f, a31 = 0.f, a32 = 0.f, a33 = 0.f;
    const float4* Wof4 = reinterpret_cast<const float4*>(Wo);
    if (sl < na) {
#pragma unroll 4
      for (int k = 0; k < 128; ++k) {
        const float4 w4 = Wof4[k * 32 + hl];
        const float f0 = s_x[at0 * 128 + k], f1 = s_x[at1 * 128 + k];
        const float f2 = s_x[at2 * 128 + k], f3 = s_x[at3 * 128 + k];
        a00 = fmaf(f0, w4.x, a00); a01 = fmaf(f0, w4.y, a01);
        a02 = fmaf(f0, w4.z, a02); a03 = fmaf(f0, w4.w, a03);
        a10 = fmaf(f1, w4.x, a10); a11 = fmaf(f1, w4.y, a11);
        a12 = fmaf(f1, w4.z, a12); a13 = fmaf(f1, w4.w, a13);
        a20 = fmaf(f2, w4.x, a20); a21 = fmaf(f2, w4.y, a21);
        a22 = fmaf(f2, w4.z, a22); a23 = fmaf(f2, w4.w, a23);
        a30 = fmaf(f3, w4.x, a30); a31 = fmaf(f3, w4.y, a31);
        a32 = fmaf(f3, w4.z, a32); a33 = fmaf(f3, w4.w, a33);
      }
    }
#pragma unroll
    for (int kk = 0; kk < 6; ++kk) {
      const float4 w4 = Wof4[(128 + kk) * 32 + hl];
      const float f0 = s_bsum[at0 * 8 + kk], f1 = s_bsum[at1 * 8 + kk];
      const float f2 = s_bsum[at2 * 8 + kk], f3 = s_bsum[at3 * 8 + kk];
      a00 = fmaf(f0, w4.x, a00); a01 = fmaf(f0, w4.y, a01);
      a02 = fmaf(f0, w4.z, a02); a03 = fmaf(f0, w4.w, a03);
      a10 = fmaf(f1, w4.x, a10); a11 = fmaf(f1, w4.y, a11);
      a12 = fmaf(f1, w4.z, a12); a13 = fmaf(f1, w4.w, a13);
      a20 = fmaf(f2, w4.x, a20); a21 = fmaf(f2, w4.y, a21);
      a22 = fmaf(f2, w4.z, a22); a23 = fmaf(f2, w4.w, a23);
      a30 = fmaf(f3, w4.x, a30); a31 = fmaf(f3, w4.y, a31);
      a32 = fmaf(f3, w4.z, a32); a33 = fmaf(f3, w4.w, a33);
    }
    const float4 bo4 = *reinterpret_cast<const float4*>(bo + c0);
    *reinterpret_cast<float4*>(&s_x[at0 * 128 + c0]) =
        make_float4(a00 + bo4.x, a01 + bo4.y, a02 + bo4.z, a03 + bo4.w);
    *reinterpret_cast<float4*>(&s_x[at1 * 128 + c0]) =
        make_float4(a10 + bo4.x, a11 + bo4.y, a12 + bo4.z, a13 + bo4.w);
    *reinterpret_cast<float4*>(&s_x[at2 * 128 + c0]) =
        make_float4(a20 + bo4.x, a21 + bo4.y, a22 + bo4.z, a23 + bo4.w);
    *reinterpret_cast<float4*>(&s_x[at3 * 128 + c0]) =
        make_float4(a30 + bo4.x, a31 + bo4.y, a32 + bo4.z, a33 + bo4.w);
  }
  __syncthreads();

  // ---------------- P6: per-atom softmax over 128, 8 lanes/atom, in registers ---------
  {
    const int a = tid >> 3, q = tid & 7;     // 64 atoms x 8 lanes
    float* base = &s_x[a * 128 + q * 16];
    const float4 v0 = *reinterpret_cast<const float4*>(base + ((0 + tid) & 3) * 4);
    const float4 v1 = *reinterpret_cast<const float4*>(base + ((1 + tid) & 3) * 4);
    const float4 v2 = *reinterpret_cast<const float4*>(base + ((2 + tid) & 3) * 4);
    const float4 v3 = *reinterpret_cast<const float4*>(base + ((3 + tid) & 3) * 4);
    float mx = fmaxf(fmaxf(fmaxf(v0.x, v0.y), fmaxf(v0.z, v0.w)),
                     fmaxf(fmaxf(v1.x, v1.y), fmaxf(v1.z, v1.w)));
    mx = fmaxf(mx, fmaxf(fmaxf(fmaxf(v2.x, v2.y), fmaxf(v2.z, v2.w)),
                         fmaxf(fmaxf(v3.x, v3.y), fmaxf(v3.z, v3.w))));
    mx = fmaxf(mx, __shfl_xor(mx, 1));
    mx = fmaxf(mx, __shfl_xor(mx, 2));
    mx = fmaxf(mx, __shfl_xor(mx, 4));
    float4 e0, e1, e2, e3;
    e0.x = __expf(v0.x - mx); e0.y = __expf(v0.y - mx); e0.z = __expf(v0.z - mx); e0.w = __expf(v0.w - mx);
    e1.x = __expf(v1.x - mx); e1.y = __expf(v1.y - mx); e1.z = __expf(v1.z - mx); e1.w = __expf(v1.w - mx);
    e2.x = __expf(v2.x - mx); e2.y = __expf(v2.y - mx); e2.z = __expf(v2.z - mx); e2.w = __expf(v2.w - mx);
    e3.x = __expf(v3.x - mx); e3.y = __expf(v3.y - mx); e3.z = __expf(v3.z - mx); e3.w = __expf(v3.w - mx);
    float sm = e0.x + e0.y + e0.z + e0.w;
    sm += e1.x + e1.y + e1.z + e1.w;
    sm += e2.x + e2.y + e2.z + e2.w;
    sm += e3.x + e3.y + e3.z + e3.w;
    *reinterpret_cast<float4*>(base + ((0 + tid) & 3) * 4) = e0;
    *reinterpret_cast<float4*>(base + ((1 + tid) & 3) * 4) = e1;
    *reinterpret_cast<float4*>(base + ((2 + tid) & 3) * 4) = e2;
    *reinterpret_cast<float4*>(base + ((3 + tid) & 3) * 4) = e3;
    sm += __shfl_xor(sm, 1);
    sm += __shfl_xor(sm, 2);
    sm += __shfl_xor(sm, 4);
    if (q == 0) s_rsum[a] = (s_deg[a] != 0) ? (1.f / sm) : 0.f;
  }
  __syncthreads();

  // ---------------- P7: fingerprint (4 partials x 128, aliases dead s_sa) -------------
  {
    const int c = tid & 127, quarter = tid >> 7;   // 0..3
    float s = 0.f;
    for (int a2 = quarter * 16; a2 < quarter * 16 + 16; ++a2)
      s = fmaf(s_x[a2 * 128 + c], s_rsum[a2], s);
    s_fp[quarter * 128 + c] = s;
  }
  __syncthreads();
  if (tid < 128) s_fp[tid] += s_fp[128 + tid] + s_fp[256 + tid] + s_fp[384 + tid];
  __syncthreads();

  // ---------------- P8: MLP head ------------------------------------------------------
  if (tid < 64) {
    float acc = bm1[tid];
    for (int k = 0; k < 128; ++k) acc = fmaf(s_fp[k], Wm1[k * 64 + tid], acc);
    s_h1[tid] = fmaxf(acc, 0.f);
  }
  __syncthreads();
  if (tid < 32) {
    float acc = bm2[tid];
    for (int k = 0; k < 64; ++k) acc = fmaf(s_h1[k], Wm2[k * 32 + tid], acc);
    s_h2[tid] = fmaxf(acc, 0.f);
  }
  __syncthreads();
  if (tid < 64) {
    float p = (tid < 32) ? s_h2[tid] * Wm3[tid] : 0.f;
#pragma unroll
    for (int off = 32; off > 0; off >>= 1) p += __shfl_xor(p, off);
    if (tid == 0) out[b] = p + bm3[0];
  }
}

extern "C" void kernel_launch(void* const* d_in, const int* in_sizes, int n_in,
                              void* d_out, int out_size, void* d_ws, size_t ws_size,
                              hipStream_t stream) {
  const float* atoms = (const float*)d_in[0];
  const float* bonds = (const float*)d_in[1];
  const int*   edges = (const int*)d_in[2];
  const float* W1  = (const float*)d_in[3];
  const float* b1  = (const float*)d_in[4];
  const float* W2  = (const float*)d_in[5];
  const float* b2  = (const float*)d_in[6];
  const float* Wo  = (const float*)d_in[7];
  const float* bo  = (const float*)d_in[8];
  const float* Wm1 = (const float*)d_in[9];
  const float* bm1 = (const float*)d_in[10];
  const float* Wm2 = (const float*)d_in[11];
  const float* bm2 = (const float*)d_in[12];
  const float* Wm3 = (const float*)d_in[13];
  const float* bm3 = (const float*)d_in[14];
  float* out = (float*)d_out;

  const int B = out_size;  // 4096 molecules
  qsar_fused<<<dim3(B), dim3(512), 0, stream>>>(
      atoms, bonds, edges, W1, b1, W2, b2, Wo, bo,
      Wm1, bm1, Wm2, bm2, Wm3, bm3, out);
}